// Round 6
// baseline (979.280 us; speedup 1.0000x reference)
//
#include <hip/hip_runtime.h>
#include <math.h>

// ---------------- problem constants ----------------
#define NLAY 120         // LSTM layers
#define TT   1016        // LSTM time steps (1024 - 4 - 4)
#define NB   64          // batches of 16 steps
#define RB   8           // L3 ring depth in batches (power of 2)
#define IRS  32          // intra-block inter-wave LDS ring slots (power of 2)
#define TPB  384         // 6 waves x 64 lanes; wave = 5 layers x 12 hidden (lanes 60-63 idle)
#define BIGF (1 << 20)

typedef float v2f __attribute__((ext_vector_type(2)));

__device__ __forceinline__ float fast_rcp(float x) { return __builtin_amdgcn_rcpf(x); }
__device__ __forceinline__ float fast_sig(float x) { return fast_rcp(1.f + __expf(-x)); }
__device__ __forceinline__ float fast_tanh(float x) { return 1.f - 2.f * fast_rcp(1.f + __expf(2.f * x)); }

// agent-scope relaxed poll (global flags); s_sleep on miss; watchdog fails loud, never hangs
__device__ __forceinline__ int poll_ge_ag(const int* p, int tgt, int cur) {
  long g = 0;
  while (cur < tgt) {
    cur = __hip_atomic_load(p, __ATOMIC_RELAXED, __HIP_MEMORY_SCOPE_AGENT);
    if (cur >= tgt) break;
    __builtin_amdgcn_s_sleep(1);
    if (++g > 400000L) break;
  }
  return cur;
}
// workgroup-scope relaxed poll on an LDS flag
__device__ __forceinline__ int poll_ge_wg(const int* p, int tgt, int cur) {
  long g = 0;
  while (cur < tgt) {
    cur = __hip_atomic_load(p, __ATOMIC_RELAXED, __HIP_MEMORY_SCOPE_WORKGROUP);
    if (cur >= tgt) break;
    __builtin_amdgcn_s_sleep(1);
    if (++g > 400000L) break;
  }
  return cur;
}

// ---------------- conv1d(6->6,K=5,valid) + bias, accumulate BN stats ----------------
__global__ void k_conv(const float* __restrict__ xin, const float* __restrict__ cw,
                       const float* __restrict__ cb, const float* __restrict__ aff,
                       float* __restrict__ yout, float* __restrict__ stat,
                       int Tin, int Tout, int use_aff)
{
  const int bx = blockIdx.x;            // 0..383 : b*6+co
  const int b = bx / 6, co = bx - b * 6;
  const int tid = threadIdx.x;          // 256
  __shared__ float wsh[30];
  __shared__ float ssh[6], shsh[6];
  if (tid < 30) wsh[tid] = cw[co * 30 + tid];
  if (tid < 6) {
    ssh[tid]  = use_aff ? aff[tid] : 1.f;
    shsh[tid] = use_aff ? aff[6 + tid] : 0.f;
  }
  __syncthreads();
  const float bias = cb[co];
  float lsum = 0.f, lsq = 0.f;
  for (int t = tid; t < Tout; t += 256) {
    float acc = bias;
#pragma unroll
    for (int ci = 0; ci < 6; ++ci) {
      const float* xr = xin + ((size_t)b * 6 + ci) * Tin + t;
      const float s = ssh[ci], sh = shsh[ci];
#pragma unroll
      for (int k = 0; k < 5; ++k) {
        float v = xr[k];
        if (use_aff) v = fmaxf(fmaf(s, v, sh), 0.f);
        acc += wsh[ci * 5 + k] * v;
      }
    }
    yout[((size_t)b * 6 + co) * Tout + t] = acc;
    lsum += acc; lsq += acc * acc;
  }
  __shared__ float rs[256], rq[256];
  rs[tid] = lsum; rq[tid] = lsq;
  __syncthreads();
  for (int s = 128; s > 0; s >>= 1) {
    if (tid < s) { rs[tid] += rs[tid + s]; rq[tid] += rq[tid + s]; }
    __syncthreads();
  }
  if (tid == 0) { atomicAdd(&stat[co], rs[0]); atomicAdd(&stat[6 + co], rq[0]); }
}

// ---------------- finalize BN: stats -> per-channel scale/shift ----------------
__global__ void k_finalize(const float* __restrict__ stat,
                           const float* __restrict__ gamma, const float* __restrict__ beta,
                           float* __restrict__ aff, float invN)
{
  const int c = threadIdx.x;
  if (c < 6) {
    float mean = stat[c] * invN;
    float var  = stat[6 + c] * invN - mean * mean;
    float sc   = gamma[c] * rsqrtf(var + 1e-5f);
    aff[c]     = sc;
    aff[6 + c] = fmaf(-mean, sc, beta[c]);
  }
}

// ---------------- BN2+ReLU + attn projection (6->12) + ReLU; write seq0[t][b*12+j] ----------------
__global__ void k_attn(const float* __restrict__ y2, const float* __restrict__ aff2,
                       const float* __restrict__ aw, const float* __restrict__ ab,
                       float* __restrict__ seq0)
{
  const int t = blockIdx.x;             // 0..1015
  const int tid = threadIdx.x;          // 0..767
  __shared__ float zb[6 * 64];
  if (tid < 384) {
    const int c = tid >> 6, bb = tid & 63;
    float v = y2[((size_t)bb * 6 + c) * TT + t];
    zb[c * 64 + bb] = fmaxf(fmaf(aff2[c], v, aff2[6 + c]), 0.f);
  }
  __syncthreads();
  const int b = tid / 12, j = tid - b * 12;
  float acc = ab[j];
#pragma unroll
  for (int c = 0; c < 6; ++c) acc += aw[j * 6 + c] * zb[c * 64 + b];
  seq0[(size_t)t * 768 + tid] = fmaxf(acc, 0.f);
}

// ---------------- 120-layer LSTM: free-running waves, register data plane ----------------
// grid = 256 blocks: bid = chain*4 + seg. Wave w = 5-layer stage; lane (p,j) = layer w*5+p.
// Diagonal: at step s, group p computes t = s - p.
// h lives in a VGPR; own-group h and prev-group x gathered via ds_bpermute (register
// to register, no LDS store->load round trip). Group 0's x still comes from iring/xring.
// Wave->wave: iring + RELAXED LDS flags, cadence 4. Block->block: 16-step L3 ring batches.
__global__ __launch_bounds__(TPB, 2) void k_lstm(
    const float* __restrict__ wih, const float* __restrict__ whh,
    const float* __restrict__ bih, const float* __restrict__ bhh,
    const float* __restrict__ seq0, float* __restrict__ ring,
    int* __restrict__ prog, int* __restrict__ cons,
    float* __restrict__ hfin)
{
  const int bid  = blockIdx.x;         // 0..255
  const int c    = bid >> 2;           // chain = batch element
  const int seg  = bid & 3;
  const int tid  = threadIdx.x;
  const int w    = tid >> 6;           // wave 0..5
  const int lane = tid & 63;
  const int p    = lane / 12;          // 0..5 (5 = pad group, never read by anyone)
  const int j    = lane - p * 12;
  const bool act = (p < 5);
  const int pc   = act ? p : 0;        // clamped for safe addressing
  const int l    = seg * 30 + w * 5 + pc;

  // ---- LDS (cross-wave only; intra-wave data plane is registers + bpermute) ----
  __shared__ __align__(16) float iring[5][IRS][12];     // wave w -> w+1
  __shared__ __align__(16) float xring[2][16][12];      // feeder input (wave 0 private)
  __shared__ __align__(16) float oring[16][12];         // tailer staging (wave 5 private)
  __shared__ int pflag[6];                              // produced-count (posted by w<5)
  __shared__ int cflag[8];                              // consumed-count (posted by w>0)
  float* xrf = &xring[0][0][0];

  if (tid < 6) pflag[tid] = 0;
  if (tid < 8) cflag[tid] = 0;
  __syncthreads();   // ONE barrier, before the main loop only

  // ---- bpermute byte-addresses (loop-invariant VGPRs) ----
  int ah_addr[12], ax_addr[12];
#pragma unroll
  for (int k = 0; k < 12; ++k) {
    ah_addr[k] = (pc * 12 + k) * 4;                       // own group lanes
    ax_addr[k] = (((pc > 0) ? pc - 1 : 0) * 12 + k) * 4;  // prev group lanes (p==0: unused)
  }

  // ---- gate weights as (i,f),(g,o) float2 pairs -> v_pk_fma_f32 ----
  v2f wx_if[12], wx_go[12], wh_if[12], wh_go[12];
  v2f b_if = (v2f){0.f, 0.f}, b_go = (v2f){0.f, 0.f};
  if (act) {
    const float* wi = wih + l * 576;
    const float* wh = whh + l * 576;
#pragma unroll
    for (int k = 0; k < 12; ++k) {
      wx_if[k] = (v2f){ wi[(j     ) * 12 + k], wi[(j + 12) * 12 + k] };
      wx_go[k] = (v2f){ wi[(j + 24) * 12 + k], wi[(j + 36) * 12 + k] };
      wh_if[k] = (v2f){ wh[(j     ) * 12 + k], wh[(j + 12) * 12 + k] };
      wh_go[k] = (v2f){ wh[(j + 24) * 12 + k], wh[(j + 36) * 12 + k] };
    }
    const float* ba = bih + l * 48;
    const float* bb = bhh + l * 48;
    b_if = (v2f){ ba[j]      + bb[j],      ba[j + 12] + bb[j + 12] };
    b_go = (v2f){ ba[j + 24] + bb[j + 24], ba[j + 36] + bb[j + 36] };
  }

  // ---- feeder / tailer plumbing ----
  const int hop_in  = c * 3 + seg - 1;                 // valid if seg>0
  const int hop_out = c * 3 + seg;                     // valid if seg<3
  const float* rin  = ring + (size_t)((seg > 0) ? hop_in : 0) * (RB * 192);
  float*       rout = ring + (size_t)((seg < 3) ? hop_out : 0) * (RB * 192);
  const bool is_feeder = (w == 0);
  const bool is_tailer = (w == 5) && (seg < 3);

  const int f0 = lane, f1 = lane + 64, f2 = lane + 128;   // cooperative 192-float copy
  const int s0o0 = (f0 / 12) * 768 + (f0 % 12);           // seq0 gather offsets
  const int s0o1 = (f1 / 12) * 768 + (f1 % 12);
  const int s0o2 = (f2 / 12) * 768 + (f2 % 12);

  auto ld_batch = [&](int m, float* d) {
    if (seg == 0) {
      const float* b = seq0 + (size_t)m * 16 * 768 + c * 12;
      d[0] = b[s0o0]; d[1] = b[s0o1]; d[2] = b[s0o2];
    } else {
      const float* b = rin + (m & (RB - 1)) * 192;
      d[0] = __hip_atomic_load(b + f0, __ATOMIC_RELAXED, __HIP_MEMORY_SCOPE_AGENT);
      d[1] = __hip_atomic_load(b + f1, __ATOMIC_RELAXED, __HIP_MEMORY_SCOPE_AGENT);
      d[2] = __hip_atomic_load(b + f2, __ATOMIC_RELAXED, __HIP_MEMORY_SCOPE_AGENT);
    }
  };

  float pend[3] = {0.f, 0.f, 0.f};
  int kp = 0, kcons = 0;
  if (is_feeder) {
    if (seg > 0) kp = poll_ge_ag(&prog[hop_in], 2, 0);
    float cur[3];
    ld_batch(0, cur);
    ld_batch(1, pend);
    xrf[f0] = cur[0]; xrf[f1] = cur[1]; xrf[f2] = cur[2];   // batch 0 -> buffer 0
  }

  float cst = 0.f, hn = 0.f;
  int pcache = 0, ccache = 0;

  // ---- one LSTM step; `guard` constant-folds per call site ----
  auto step = [&](int s, bool guard) __attribute__((always_inline)) {
    // register->register gather: own-group h and prev-group x from lanes' hn
    const int hbits = __float_as_int(hn);
    float hh[12], xx[12];
#pragma unroll
    for (int k = 0; k < 12; ++k)
      xx[k] = __int_as_float(__builtin_amdgcn_ds_bpermute(ax_addr[k], hbits));
#pragma unroll
    for (int k = 0; k < 12; ++k)
      hh[k] = __int_as_float(__builtin_amdgcn_ds_bpermute(ah_addr[k], hbits));
    if (p == 0) {   // group 0: x comes from the cross-wave / input ring
      const float4* xp = (w == 0)
          ? (const float4*)(xrf + ((s >> 4) & 1) * 192 + (s & 15) * 12)
          : (const float4*)(&iring[w - 1][s & (IRS - 1)][0]);
      float4 a = xp[0], b4 = xp[1], d = xp[2];
      xx[0]=a.x; xx[1]=a.y; xx[2]=a.z; xx[3]=a.w;
      xx[4]=b4.x; xx[5]=b4.y; xx[6]=b4.z; xx[7]=b4.w;
      xx[8]=d.x; xx[9]=d.y; xx[10]=d.z; xx[11]=d.w;
    }

    // 8 half-depth chains (latency ~28 vs 48), then combine
    v2f xifa = b_if, xgoa = b_go;
    v2f xifb = (v2f){0.f,0.f}, xgob = (v2f){0.f,0.f};
    v2f hifa = (v2f){0.f,0.f}, hgoa = (v2f){0.f,0.f};
    v2f hifb = (v2f){0.f,0.f}, hgob = (v2f){0.f,0.f};
#pragma unroll
    for (int k = 0; k < 6; ++k) {
      v2f xk = { xx[k], xx[k] },     xk2 = { xx[k + 6], xx[k + 6] };
      v2f hk = { hh[k], hh[k] },     hk2 = { hh[k + 6], hh[k + 6] };
      xifa = __builtin_elementwise_fma(wx_if[k],     xk,  xifa);
      xifb = __builtin_elementwise_fma(wx_if[k + 6], xk2, xifb);
      xgoa = __builtin_elementwise_fma(wx_go[k],     xk,  xgoa);
      xgob = __builtin_elementwise_fma(wx_go[k + 6], xk2, xgob);
      hifa = __builtin_elementwise_fma(wh_if[k],     hk,  hifa);
      hifb = __builtin_elementwise_fma(wh_if[k + 6], hk2, hifb);
      hgoa = __builtin_elementwise_fma(wh_go[k],     hk,  hgoa);
      hgob = __builtin_elementwise_fma(wh_go[k + 6], hk2, hgob);
    }
    v2f aif = (xifa + hifa) + (xifb + hifb);
    v2f ago = (xgoa + hgoa) + (xgob + hgob);
    float ig = fast_sig(aif.x);
    float fg = fast_sig(aif.y);
    float gg = fast_tanh(ago.x);
    float og = fast_sig(ago.y);

    if (!guard) {
      cst = fg * cst + ig * gg;
      hn  = og * fast_tanh(cst);
      if (p == 4) {            // t = s - 4, uniform slot math
        if (w < 5) iring[w][(s - 4) & (IRS - 1)][j] = hn;
        else if (seg < 3) oring[(s - 4) & 15][j] = hn;
      }
    } else {
      const int t = s - pc;
      const bool run = act && (t >= 0) && (t < TT);
      if (run) {
        cst = fg * cst + ig * gg;
        hn  = og * fast_tanh(cst);
        if (p == 4) {
          if (w < 5) iring[w][t & (IRS - 1)][j] = hn;
          else if (seg < 3) oring[t & 15][j] = hn;
        }
        if (t == TT - 1) hfin[l * 768 + c * 12 + j] = hn;
      }
    }

    // tailer: flush a completed 16-step batch to the L3 ring (wave-uniform branch)
    if (is_tailer) {
      const int t4 = s - 4;
      if (t4 >= 0 && t4 < TT && (((t4 & 15) == 15) || t4 == TT - 1)) {
        const int m4 = t4 >> 4;
        if (kcons < m4 - (RB - 1) + 1)
          kcons = poll_ge_ag(&cons[hop_out], m4 - RB + 1, kcons);
        const float* orf = &oring[0][0];
        float o0 = orf[f0], o1 = orf[f1], o2 = orf[f2];
        float* d = rout + (m4 & (RB - 1)) * 192;
        __hip_atomic_store(d + f0, o0, __ATOMIC_RELAXED, __HIP_MEMORY_SCOPE_AGENT);
        __hip_atomic_store(d + f1, o1, __ATOMIC_RELAXED, __HIP_MEMORY_SCOPE_AGENT);
        __hip_atomic_store(d + f2, o2, __ATOMIC_RELAXED, __HIP_MEMORY_SCOPE_AGENT);
        if (lane == 0)   // RELEASE: drains this wave's 3 stores; other waves keep running
          __hip_atomic_store(&prog[hop_out], m4 + 1, __ATOMIC_RELEASE, __HIP_MEMORY_SCOPE_AGENT);
      }
    }
  };

  for (int s4 = 0; s4 < 1024; s4 += 4) {
    // ---- batch boundary: feeder publishes batch m+1, starts loads for m+2 ----
    if (is_feeder && (s4 & 15) == 0) {
      const int m = s4 >> 4;
      if (m + 1 < NB) {
        float* xd = xrf + ((m + 1) & 1) * 192;
        xd[f0] = pend[0]; xd[f1] = pend[1]; xd[f2] = pend[2];
      }
      if (m + 2 < NB) {
        if (seg > 0 && kp < m + 3) kp = poll_ge_ag(&prog[hop_in], m + 3, kp);
        ld_batch(m + 2, pend);     // stays in flight for the next 16 steps
      }
      if (seg > 0 && lane == 0)
        __hip_atomic_store(&cons[hop_in], m, __ATOMIC_RELAXED, __HIP_MEMORY_SCOPE_AGENT);
    }

    // ---- relaxed LDS flag checks, once per 4 steps ----
    if (w > 0 && s4 < TT) {
      const int tgt = (s4 + 4 < TT) ? (s4 + 4) : TT;
      if (pcache < tgt) {
        pcache = poll_ge_wg(&pflag[w - 1], tgt, pcache);
        asm volatile("" ::: "memory");
      }
    }
    if (w < 5 && s4 >= 36) {
      const int tgt = s4 - 32;
      if (ccache < tgt) {
        ccache = poll_ge_wg(&cflag[w + 1], tgt, ccache);
        asm volatile("" ::: "memory");
      }
    }

    if (s4 >= 4 && s4 < 1012) {
      step(s4 + 0, false); step(s4 + 1, false); step(s4 + 2, false); step(s4 + 3, false);
    } else {
      step(s4 + 0, true);  step(s4 + 1, true);  step(s4 + 2, true);  step(s4 + 3, true);
    }

    // ---- relaxed flag posts (DS pipe in-order per wave orders data before flag) ----
    if (lane == 0) {
      asm volatile("" ::: "memory");
      if (w < 5)
        __hip_atomic_store(&pflag[w], s4, __ATOMIC_RELAXED, __HIP_MEMORY_SCOPE_WORKGROUP);
      if (w > 0 && s4 + 3 < TT)
        __hip_atomic_store(&cflag[w], s4 + 4, __ATOMIC_RELAXED, __HIP_MEMORY_SCOPE_WORKGROUP);
    }
  }

  // ---- epilogue: unblock any remaining pollers ----
  if (lane == 0) {
    asm volatile("" ::: "memory");
    if (w < 5) __hip_atomic_store(&pflag[w], BIGF, __ATOMIC_RELAXED, __HIP_MEMORY_SCOPE_WORKGROUP);
    if (w > 0) __hip_atomic_store(&cflag[w], BIGF, __ATOMIC_RELAXED, __HIP_MEMORY_SCOPE_WORKGROUP);
    if (is_feeder && seg > 0)
      __hip_atomic_store(&cons[hop_in], BIGF, __ATOMIC_RELAXED, __HIP_MEMORY_SCOPE_AGENT);
  }
}

// ---------------- head: lin1+relu, lin2+relu, mu, softplus(sigma) ----------------
__global__ void k_head(const float* __restrict__ hfin,
                       const float* __restrict__ w1, const float* __restrict__ b1,
                       const float* __restrict__ w2, const float* __restrict__ b2,
                       const float* __restrict__ wm, const float* __restrict__ bm,
                       const float* __restrict__ wsg, const float* __restrict__ bsg,
                       float* __restrict__ out)
{
  const int tid = threadIdx.x;
  __shared__ float s1[144], s2[144], sm[144], ss[144];
  __shared__ float v1[12], v2[12], vm[12], vs[12];
  if (tid < 144) { s1[tid] = w1[tid]; s2[tid] = w2[tid]; sm[tid] = wm[tid]; ss[tid] = wsg[tid]; }
  if (tid < 12)  { v1[tid] = b1[tid]; v2[tid] = b2[tid]; vm[tid] = bm[tid]; vs[tid] = bsg[tid]; }
  __syncthreads();
  const int r = blockIdx.x * 256 + tid;   // 0..7679 = b*120 + l
  const int b = r / 120, l = r - b * 120;
  float h[12];
#pragma unroll
  for (int k = 0; k < 12; ++k) h[k] = hfin[l * 768 + b * 12 + k];
  float u1[12];
#pragma unroll
  for (int u = 0; u < 12; ++u) {
    float a = v1[u];
#pragma unroll
    for (int k = 0; k < 12; ++k) a += s1[u * 12 + k] * h[k];
    u1[u] = fmaxf(a, 0.f);
  }
  float u2[12];
#pragma unroll
  for (int u = 0; u < 12; ++u) {
    float a = v2[u];
#pragma unroll
    for (int k = 0; k < 12; ++k) a += s2[u * 12 + k] * u1[k];
    u2[u] = fmaxf(a, 0.f);
  }
  const size_t base = (size_t)r * 12;
#pragma unroll
  for (int u = 0; u < 12; ++u) out[base + u] = u2[u];
#pragma unroll
  for (int u = 0; u < 12; ++u) {
    float a = vm[u];
#pragma unroll
    for (int k = 0; k < 12; ++k) a += sm[u * 12 + k] * u2[k];
    out[92160 + base + u] = a;
  }
#pragma unroll
  for (int u = 0; u < 12; ++u) {
    float a = vs[u];
#pragma unroll
    for (int k = 0; k < 12; ++k) a += ss[u * 12 + k] * u2[k];
    out[184320 + base + u] = fmaxf(a, 0.f) + log1pf(expf(-fabsf(a)));
  }
}

// ---------------- launcher ----------------
extern "C" void kernel_launch(void* const* d_in, const int* in_sizes, int n_in,
                              void* d_out, int out_size, void* d_ws, size_t ws_size,
                              hipStream_t stream)
{
  const float* x   = (const float*)d_in[0];
  const float* c1w = (const float*)d_in[1];
  const float* c1b = (const float*)d_in[2];
  const float* g1  = (const float*)d_in[3];
  const float* be1 = (const float*)d_in[4];
  const float* c2w = (const float*)d_in[5];
  const float* c2b = (const float*)d_in[6];
  const float* g2  = (const float*)d_in[7];
  const float* be2 = (const float*)d_in[8];
  const float* aw  = (const float*)d_in[9];
  const float* ab  = (const float*)d_in[10];
  const float* wih = (const float*)d_in[11];
  const float* whh = (const float*)d_in[12];
  const float* bih = (const float*)d_in[13];
  const float* bhh = (const float*)d_in[14];
  const float* l1w = (const float*)d_in[15];
  const float* l1b = (const float*)d_in[16];
  const float* l2w = (const float*)d_in[17];
  const float* l2b = (const float*)d_in[18];
  const float* muw = (const float*)d_in[19];
  const float* mub = (const float*)d_in[20];
  const float* sgw = (const float*)d_in[21];
  const float* sgb = (const float*)d_in[22];

  float* ws    = (float*)d_ws;
  float* stat1 = ws;                    // 12
  float* stat2 = ws + 12;               // 12
  float* aff1  = ws + 24;               // 12
  float* aff2  = ws + 36;               // 12
  int*   prog  = (int*)(ws + 64);       // 192 used
  int*   cons  = (int*)(ws + 304);      // 192 used
  float* y1    = ws + 576;              // 64*6*1020
  float* y2    = y1 + 391680;           // 64*6*1016
  float* seq0  = y2 + 390144;           // 1016*768
  float* ring  = seq0 + 780288;         // 192 hops * 8 batches * 192 floats
  float* hfin  = ring + (size_t)192 * RB * 192;   // 120*768

  hipMemsetAsync(d_ws, 0, 576 * sizeof(float), stream);  // zero stats + flags

  k_conv<<<384, 256, 0, stream>>>(x, c1w, c1b, nullptr, y1, stat1, 1024, 1020, 0);
  k_finalize<<<1, 64, 0, stream>>>(stat1, g1, be1, aff1, 1.f / 65280.f);
  k_conv<<<384, 256, 0, stream>>>(y1, c2w, c2b, aff1, y2, stat2, 1020, 1016, 1);
  k_finalize<<<1, 64, 0, stream>>>(stat2, g2, be2, aff2, 1.f / 65024.f);
  k_attn<<<1016, 768, 0, stream>>>(y2, aff2, aw, ab, seq0);
  k_lstm<<<256, TPB, 0, stream>>>(wih, whh, bih, bhh, seq0, ring, prog, cons, hfin);
  k_head<<<30, 256, 0, stream>>>(hfin, l1w, l1b, l2w, l2b, muw, mub, sgw, sgb, (float*)d_out);
}